// Round 1
// baseline (96.888 us; speedup 1.0000x reference)
//
#include <hip/hip_runtime.h>
#include <hip/hip_bf16.h>
#include <cstdint>
#include <cstddef>

// Problem constants (B=4, H=16, S=4096, E=128)
#define S_LEN 4096
#define E_DIM 128
#define NROWS (4 * 16 * 4096)   // 262144 token rows

typedef __attribute__((ext_vector_type(8))) short bh8;   // 8 bf16 (4 VGPRs) MFMA frag
typedef __attribute__((ext_vector_type(4))) float f4;    // MFMA accumulator

__device__ __forceinline__ unsigned short f2bf(float f) {
    union { float f; uint32_t u; } v; v.f = f;
    uint32_t r = v.u + 0x7FFFu + ((v.u >> 16) & 1u);   // round-to-nearest-even
    return (unsigned short)(r >> 16);
}

// ---------- prologue: A = (S - S^T)/2, plus cos/sin table ----------
__global__ void k_prep(const float* __restrict__ Sc, const float* __restrict__ pos,
                       float* __restrict__ A, float* __restrict__ cosT,
                       float* __restrict__ sinT, int doTable) {
    int b = blockIdx.x;
    if (b < 16) {
        for (int e = b * 256 + threadIdx.x; e < 16384; e += 4096) {
            int i = e >> 7, j = e & 127;
            A[e] = 0.5f * (Sc[i * 128 + j] - Sc[j * 128 + i]);
        }
    } else if (doTable) {
        int t = (b - 16) * 256 + threadIdx.x;
        for (int e = t; e < S_LEN * 64; e += 64 * 256) {
            int s = e >> 6, f = e & 63;
            // freq = 10000^(-f/64) = exp2(-f * log2(10000)/64)
            float freq = exp2f(-0.20762050593046015f * (float)f);
            float ang = pos[s] * freq;
            float sv, cv;
            sincosf(ang, &sv, &cv);
            cosT[e] = cv;
            sinT[e] = sv;
        }
    }
}

// ---------- A2 = A*A (f32, tiny) ----------
__global__ void k_sq(const float* __restrict__ M, float* __restrict__ O) {
    int t = blockIdx.x * 256 + threadIdx.x;      // 32 blocks
    for (int e = t; e < 16384; e += 8192) {
        int i = e >> 7, j = e & 127;
        float acc = 0.f;
        for (int k = 0; k < 128; ++k) acc += M[i * 128 + k] * M[k * 128 + j];
        O[e] = acc;
    }
}

// ---------- A4 = A2*A2  and  M1 = (I - 2A + A2)(I + A2) ----------
__global__ void k_step2(const float* __restrict__ A, const float* __restrict__ A2,
                        float* __restrict__ A4, float* __restrict__ M1) {
    int b = blockIdx.x;                          // 64 blocks
    if (b < 32) {
        int t = b * 256 + threadIdx.x;
        for (int e = t; e < 16384; e += 8192) {
            int i = e >> 7, j = e & 127;
            float acc = 0.f;
            for (int k = 0; k < 128; ++k) acc += A2[i * 128 + k] * A2[k * 128 + j];
            A4[e] = acc;
        }
    } else {
        int t = (b - 32) * 256 + threadIdx.x;
        for (int e = t; e < 16384; e += 8192) {
            int i = e >> 7, j = e & 127;
            float acc = 0.f;
            for (int k = 0; k < 128; ++k) {
                float bik = A2[i * 128 + k] - 2.0f * A[i * 128 + k] + (k == i ? 1.0f : 0.0f);
                float ckj = A2[k * 128 + j] + (k == j ? 1.0f : 0.0f);
                acc += bik * ckj;
            }
            M1[e] = acc;
        }
    }
}

// ---------- P = M1*(I + A4);  store Q = P - I as bf16 ----------
__global__ void k_finalP(const float* __restrict__ M1, const float* __restrict__ A4,
                         unsigned short* __restrict__ Qb) {
    int t = blockIdx.x * 256 + threadIdx.x;      // 32 blocks
    for (int e = t; e < 16384; e += 8192) {
        int i = e >> 7, j = e & 127;
        float acc = M1[e];
        for (int k = 0; k < 128; ++k) acc += M1[i * 128 + k] * A4[k * 128 + j];
        if (i == j) acc -= 1.0f;                 // Q = P - I
        Qb[e] = f2bf(acc);
    }
}

// ---------- main fused kernel: out = RoPE(x + x*Q^T) ----------
template <bool USE_TABLE>
__global__ __launch_bounds__(256) void k_main(const float* __restrict__ x,
        const unsigned short* __restrict__ Qb,
        const float* __restrict__ cosT, const float* __restrict__ sinT,
        const float* __restrict__ pos, float* __restrict__ out) {
    // Q staged in LDS: 128 rows padded to 136 shorts (272 B) -> bank-uniform b128 reads
    __shared__ unsigned short Plds[128 * 136];
    #pragma unroll
    for (int i = 0; i < 8; ++i) {
        int chunk = i * 256 + threadIdx.x;       // 2048 chunks of 8 shorts (16 B)
        int row = chunk >> 4, c8 = chunk & 15;
        bh8 v = *(const bh8*)(Qb + chunk * 8);
        *(bh8*)(&Plds[row * 136 + c8 * 8]) = v;
    }
    __syncthreads();

    const int wave = threadIdx.x >> 6;
    const int lane = threadIdx.x & 63;
    const int lhi = lane >> 4, llo = lane & 15;
    const int m0 = blockIdx.x * 64 + wave * 16;  // 16-row strip per wave

    // A-fragments: A[row=llo][k = kk*32 + lhi*8 + e], 8 consecutive f32 -> bf16
    bh8 afrag[4];
    const float* xr0 = x + (size_t)(m0 + llo) * E_DIM + lhi * 8;
    #pragma unroll
    for (int kk = 0; kk < 4; ++kk) {
        f4 v0 = *(const f4*)(xr0 + kk * 32);
        f4 v1 = *(const f4*)(xr0 + kk * 32 + 4);
        bh8 a;
        a[0] = (short)f2bf(v0[0]); a[1] = (short)f2bf(v0[1]);
        a[2] = (short)f2bf(v0[2]); a[3] = (short)f2bf(v0[3]);
        a[4] = (short)f2bf(v1[0]); a[5] = (short)f2bf(v1[1]);
        a[6] = (short)f2bf(v1[2]); a[7] = (short)f2bf(v1[3]);
        afrag[kk] = a;
    }

    f4 acc[8];
    #pragma unroll
    for (int t = 0; t < 8; ++t) { f4 z = {0.f, 0.f, 0.f, 0.f}; acc[t] = z; }

    // D[m][n] = sum_k x[m][k] * Q[n][k]  (B-frag: B[k][n] = Q[n][k])
    #pragma unroll
    for (int kk = 0; kk < 4; ++kk) {
        #pragma unroll
        for (int t = 0; t < 8; ++t) {
            bh8 bfrag = *(const bh8*)(&Plds[(t * 16 + llo) * 136 + kk * 32 + lhi * 8]);
            acc[t] = __builtin_amdgcn_mfma_f32_16x16x32_bf16(afrag[kk], bfrag, acc[t], 0, 0, 0);
        }
    }

    // epilogue: xt = x + x*Q^T (f32 re-read is L1-hot), then rotate-half RoPE
    #pragma unroll
    for (int r = 0; r < 4; ++r) {
        const int m = m0 + lhi * 4 + r;          // C/D: row=(lane>>4)*4+reg, col=lane&15
        const int s = m & (S_LEN - 1);
        const float* xr = x + (size_t)m * E_DIM;
        float* orow = out + (size_t)m * E_DIM;
        float spos = 0.f;
        if constexpr (!USE_TABLE) spos = pos[s];
        #pragma unroll
        for (int t = 0; t < 4; ++t) {
            const int n = t * 16 + llo;
            const int f1 = n >> 1;
            float xt1 = acc[t][r] + xr[n];
            float xt2 = acc[t + 4][r] + xr[n + 64];
            float c1, s1, c2, s2;
            if constexpr (USE_TABLE) {
                c1 = cosT[s * 64 + f1];      s1 = sinT[s * 64 + f1];
                c2 = cosT[s * 64 + f1 + 32]; s2 = sinT[s * 64 + f1 + 32];
            } else {
                float fr1 = exp2f(-0.20762050593046015f * (float)f1);
                float fr2 = fr1 * 0.01f;     // 10000^(-32/64) = 0.01
                sincosf(spos * fr1, &s1, &c1);
                sincosf(spos * fr2, &s2, &c2);
            }
            orow[n]      = xt1 * c1 - xt2 * s1;  // j < 64:  xt*cos - xt[j+64]*sin
            orow[n + 64] = xt2 * c2 + xt1 * s2;  // j >= 64: xt*cos + xt[j-64]*sin
        }
    }
}

extern "C" void kernel_launch(void* const* d_in, const int* in_sizes, int n_in,
                              void* d_out, int out_size, void* d_ws, size_t ws_size,
                              hipStream_t stream) {
    const float* x   = (const float*)d_in[0];
    const float* pos = (const float*)d_in[1];
    const float* Sc  = (const float*)d_in[2];
    float* out = (float*)d_out;

    char* ws = (char*)d_ws;
    float* A            = (float*)(ws);                    // 64 KB
    float* A2           = (float*)(ws + 65536);            // 64 KB
    float* A4           = (float*)(ws + 131072);           // 64 KB
    float* M1           = (float*)(ws + 196608);           // 64 KB
    unsigned short* Qb  = (unsigned short*)(ws + 262144);  // 32 KB bf16
    float* cosT         = (float*)(ws + 294912);           // 1 MB
    float* sinT         = (float*)(ws + 294912 + 1048576); // 1 MB
    const size_t needTable = 294912 + 2 * 1048576;
    bool useTable = ws_size >= needTable;

    k_prep<<<80, 256, 0, stream>>>(Sc, pos, A, cosT, sinT, useTable ? 1 : 0);
    k_sq<<<32, 256, 0, stream>>>(A, A2);
    k_step2<<<64, 256, 0, stream>>>(A, A2, A4, M1);
    k_finalP<<<32, 256, 0, stream>>>(M1, A4, Qb);
    if (useTable)
        k_main<true><<<NROWS / 64, 256, 0, stream>>>(x, Qb, cosT, sinT, pos, out);
    else
        k_main<false><<<NROWS / 64, 256, 0, stream>>>(x, Qb, cosT, sinT, pos, out);
}